// Round 2
// baseline (246.963 us; speedup 1.0000x reference)
//
#include <hip/hip_runtime.h>

static constexpr int N_DIM  = 2048;
static constexpr int BGROUP = 64;                  // batch rows per block (= lanes)
static constexpr int IBLOCK = 8;                   // i-rows per wave
static constexpr int NWAVE  = 4;                   // waves per block
static constexpr int ITILE  = IBLOCK * NWAVE;      // 32 i-rows per block
static constexpr int JCHUNK = 32;                  // j's staged per chunk
static constexpr int NCHUNK = N_DIM / JCHUNK;      // 64

typedef float f32x2 __attribute__((ext_vector_type(2)));

// out[b,i] = max_j M[i,j] * x[b,j]
// lane = b (64 b's per block). Wave w owns i-rows i0..i0+7 (wave-uniform) so
// M loads are uniform-address VMEM broadcasts (VMEM pipe), x comes from LDS
// once per chunk into VGPRs and is reused across all 8 i-rows (LDS pipe light).
__global__ __launch_bounds__(256, 1)
void tropical_g(const float* __restrict__ x, const float* __restrict__ M,
                float* __restrict__ out)
{
    __shared__ float xs[2][BGROUP][JCHUNK];   // XOR-swizzled cols, double-buffered

    const int t    = threadIdx.x;
    const int lane = t & 63;
    const int w    = t >> 6;                  // wave id 0..3
    const int bg   = blockIdx.x >> 6;         // 0..3   (b-group)
    const int it   = blockIdx.x & 63;         // 0..63  (i-tile) -> same it => same XCD slot => M L2 reuse
    const int b0   = bg * BGROUP;
    const int i0   = it * ITILE + w * IBLOCK; // wave's first i-row

    const float* Mw = M + (size_t)i0 * N_DIM;

    // ---- staging helpers (thread t covers row r=t>>2, two float4 col-groups) ----
    const int sr = t >> 2;                    // 0..63
    const int sc = (t & 3) * 2;               // float4-group 0,2,4,6

    auto stage_load = [&](int jn, float4& v0, float4& v1) {
        const float* p = x + (size_t)(b0 + sr) * N_DIM + jn + sc * 4;
        v0 = *(const float4*)p;
        v1 = *(const float4*)(p + 4);
    };
    auto stage_write = [&](int s, const float4& v0, const float4& v1) {
        *(float4*)&xs[s][sr][((sc    ) ^ (sr & 7)) * 4] = v0;
        *(float4*)&xs[s][sr][((sc + 1) ^ (sr & 7)) * 4] = v1;
    };

    // ---- M rolling 4-buffer: uniform-address loads, 3 row-steps of prefetch ----
    float4 mb[4][8];
    auto mload = [&](int buf, int row, int jn) {
        const float* p = Mw + (size_t)row * N_DIM + jn;
#pragma unroll
        for (int q = 0; q < 8; ++q)
            mb[buf][q] = *(const float4*)(p + q * 4);
    };

    float accA[IBLOCK], accB[IBLOCK];
#pragma unroll
    for (int r = 0; r < IBLOCK; ++r) {
        accA[r] = -__builtin_inff();
        accB[r] = -__builtin_inff();
    }

    // ---- compute one i-row against the register-resident x chunk ----
    auto crow = [&](int buf, int r, const float4 (&xv)[8]) {
#pragma unroll
        for (int q = 0; q < 8; ++q) {
            const float4 m4 = mb[buf][q];
            const float4 xq = xv[q];
            f32x2 ma = {m4.x, m4.y}, xa = {xq.x, xq.y};
            f32x2 p0 = ma * xa;                               // v_pk_mul_f32
            accA[r] = fmaxf(fmaxf(accA[r], p0.x), p0.y);      // v_max3_f32
            f32x2 mbv = {m4.z, m4.w}, xb = {xq.z, xq.w};
            f32x2 p1 = mbv * xb;
            accB[r] = fmaxf(fmaxf(accB[r], p1.x), p1.y);
        }
    };

    // ---- prologue: stage chunk 0, prefetch M row-steps 0,1,2 ----
    {
        float4 v0, v1;
        stage_load(0, v0, v1);
        mload(0, 0, 0);
        mload(1, 1, 0);
        mload(2, 2, 0);
        stage_write(0, v0, v1);
        asm volatile("s_waitcnt lgkmcnt(0)" ::: "memory");
        __builtin_amdgcn_s_barrier();
    }

#pragma unroll 1
    for (int c = 0; c < NCHUNK; ++c) {
        // x chunk -> registers (8 ds_read_b128, swizzled: 8-way spread = b128 optimum)
        float4 xv[8];
#pragma unroll
        for (int cg = 0; cg < 8; ++cg)
            xv[cg] = *(const float4*)&xs[c & 1][lane][(cg ^ (lane & 7)) * 4];

        // issue next chunk's global x loads early (latency hides under 8-row compute)
        float4 sv0, sv1;
        const bool more = (c + 1 < NCHUNK);
        if (more) stage_load((c + 1) * JCHUNK, sv0, sv1);

#pragma unroll
        for (int r = 0; r < IBLOCK; ++r) {
            // prefetch M for row-step r+3 (same wave rows, j advances across chunks)
            const int nr = (r + 3) & 7;                 // compile-time
            const int nc = c + ((r + 3) >> 3);          // c or c+1
            if (nc < NCHUNK) mload((r + 3) & 3, nr, nc * JCHUNK);
            crow(r & 3, r, xv);
        }

        if (more) stage_write((c + 1) & 1, sv0, sv1);
        // order LDS writes vs next chunk's reads WITHOUT draining vmcnt
        // (keeps M prefetch loads in flight across the barrier)
        asm volatile("s_waitcnt lgkmcnt(0)" ::: "memory");
        __builtin_amdgcn_s_barrier();
    }

    // ---- epilogue: 8 scattered stores per lane (negligible vs compute) ----
    float* orow = out + (size_t)(b0 + lane) * N_DIM + i0;
#pragma unroll
    for (int r = 0; r < IBLOCK; ++r)
        orow[r] = fmaxf(accA[r], accB[r]);
}

extern "C" void kernel_launch(void* const* d_in, const int* in_sizes, int n_in,
                              void* d_out, int out_size, void* d_ws, size_t ws_size,
                              hipStream_t stream)
{
    const float* x = (const float*)d_in[0];
    const float* M = (const float*)d_in[1];
    float* out = (float*)d_out;

    const int B = in_sizes[0] / N_DIM;                         // 256
    dim3 grid((unsigned)((B / BGROUP) * (N_DIM / ITILE)));     // 4 * 64 = 256 blocks
    dim3 block(256);
    hipLaunchKernelGGL(tropical_g, grid, block, 0, stream, x, M, out);
}

// Round 3
// 113.360 us; speedup vs baseline: 2.1786x; 2.1786x over previous
//
#include <hip/hip_runtime.h>

static constexpr int N_DIM = 2048;
static constexpr int BB = 64;    // batch rows per block
static constexpr int BI = 128;   // i rows per block
static constexpr int BJ = 32;    // j per chunk
static constexpr int UB = 4;     // b rows per thread (strided by 16)
static constexpr int VI = 8;     // i rows per thread (contiguous)
static constexpr int XP = 36;    // padded LDS row stride (floats): bank-rotate 4

typedef float f32x2 __attribute__((ext_vector_type(2)));

// out[b,i] = max_j M[i,j]*x[b,j], j restricted to this block's segment.
// 256 threads = 16 bt x 16 it. Thread owns b-rows {bt+16u}, i-rows {it*8+v}.
// Per j-group(4): 4 x-reads + 8 M-reads (192B LDS) for 128 products -> VALU-bound.
template<int JSPLIT>
__global__ __launch_bounds__(256, 4)
void tropical_main(const float* __restrict__ x, const float* __restrict__ M,
                   float* __restrict__ dst, int B)
{
    constexpr int JRANGE = N_DIM / JSPLIT;
    constexpr int NCH = JRANGE / BJ;

    __shared__ float xs[BB][XP];
    __shared__ float Ms[BI][XP];   // logical [BI][32], cols XOR-swizzled by (row>>3)&7

    const int t  = threadIdx.x;
    const int bt = t & 15;
    const int it = t >> 4;

    const int perjs  = gridDim.x / JSPLIT;
    const int js     = blockIdx.x / perjs;
    const int rem    = blockIdx.x % perjs;
    const int itiles = N_DIM / BI;          // 16
    const int b0 = (rem / itiles) * BB;
    const int i0 = (rem % itiles) * BI;
    const int jb = js * JRANGE;

    float acc[UB][VI];
#pragma unroll
    for (int u = 0; u < UB; ++u)
#pragma unroll
        for (int v = 0; v < VI; ++v)
            acc[u][v] = -__builtin_inff();

#pragma unroll 1
    for (int ch = 0; ch < NCH; ++ch) {
        const int j0 = jb + ch * BJ;
        __syncthreads();   // WAR: previous chunk's reads done before restage
        // stage x: 64 rows x 8 f4 (2/thread), linear map -> coalesced global
#pragma unroll
        for (int q = 0; q < 2; ++q) {
            const int idx = q * 256 + t;
            const int r = idx >> 3, c = idx & 7;
            const float4 v = *(const float4*)(x + (size_t)(b0 + r) * N_DIM + j0 + c * 4);
            *(float4*)&xs[r][c * 4] = v;
        }
        // stage M: 128 rows x 8 f4 (4/thread), col ^= (row>>3)&7
#pragma unroll
        for (int q = 0; q < 4; ++q) {
            const int idx = q * 256 + t;
            const int r = idx >> 3, c = idx & 7;
            const float4 v = *(const float4*)(M + (size_t)(i0 + r) * N_DIM + j0 + c * 4);
            *(float4*)&Ms[r][(c ^ ((r >> 3) & 7)) * 4] = v;
        }
        __syncthreads();

#pragma unroll
        for (int jg = 0; jg < BJ / 4; ++jg) {
            float4 xv[UB];
#pragma unroll
            for (int u = 0; u < UB; ++u)
                xv[u] = *(const float4*)&xs[bt + 16 * u][jg * 4];   // rows bt+16u: 2-way max = free
            const int mc = (jg ^ (it & 7)) * 4;                     // matches write swizzle
#pragma unroll
            for (int v = 0; v < VI; ++v) {
                const float4 mv = *(const float4*)&Ms[it * 8 + v][mc];
                const f32x2 ml = {mv.x, mv.y}, mh = {mv.z, mv.w};
#pragma unroll
                for (int u = 0; u < UB; ++u) {
                    const f32x2 xl = {xv[u].x, xv[u].y}, xh = {xv[u].z, xv[u].w};
                    const f32x2 pl = ml * xl;   // v_pk_mul_f32
                    const f32x2 ph = mh * xh;
                    float a = acc[u][v];
                    a = fmaxf(fmaxf(a, pl.x), pl.y);   // v_max3_f32
                    a = fmaxf(fmaxf(a, ph.x), ph.y);
                    acc[u][v] = a;
                }
            }
        }
    }

    // partial write: dst[js*B + b][i], fully overwritten every launch
#pragma unroll
    for (int u = 0; u < UB; ++u) {
        float* o = dst + ((size_t)js * B + b0 + bt + 16 * u) * N_DIM + i0 + it * 8;
        *(float4*)o       = make_float4(acc[u][0], acc[u][1], acc[u][2], acc[u][3]);
        *(float4*)(o + 4) = make_float4(acc[u][4], acc[u][5], acc[u][6], acc[u][7]);
    }
}

template<int JSPLIT>
__global__ __launch_bounds__(256)
void tropical_comb(const float* __restrict__ part, float* __restrict__ out, int total4)
{
    const int idx = blockIdx.x * 256 + threadIdx.x;
    if (idx >= total4) return;
    const float4* p = (const float4*)part;
    float4 a = p[idx];
#pragma unroll
    for (int s = 1; s < JSPLIT; ++s) {
        const float4 v = p[idx + (size_t)s * total4];
        a.x = fmaxf(a.x, v.x); a.y = fmaxf(a.y, v.y);
        a.z = fmaxf(a.z, v.z); a.w = fmaxf(a.w, v.w);
    }
    ((float4*)out)[idx] = a;
}

extern "C" void kernel_launch(void* const* d_in, const int* in_sizes, int n_in,
                              void* d_out, int out_size, void* d_ws, size_t ws_size,
                              hipStream_t stream)
{
    const float* x = (const float*)d_in[0];
    const float* M = (const float*)d_in[1];
    float* out = (float*)d_out;

    const int B = in_sizes[0] / N_DIM;                 // 256
    const int base = (B / BB) * (N_DIM / BI);          // 4*16 = 64 blocks per j-segment
    const size_t slab = (size_t)B * N_DIM * sizeof(float);
    const int total4 = B * N_DIM / 4;
    const int cblocks = (total4 + 255) / 256;

#define RUN_JS(JS)                                                                      \
    do {                                                                                \
        float* dst = (JS == 1) ? out : (float*)d_ws;                                    \
        hipLaunchKernelGGL(tropical_main<JS>, dim3(base * JS), dim3(256), 0, stream,    \
                           x, M, dst, B);                                               \
        if (JS > 1)                                                                     \
            hipLaunchKernelGGL(tropical_comb<JS>, dim3(cblocks), dim3(256), 0, stream,  \
                               (const float*)d_ws, out, total4);                        \
    } while (0)

    if      (ws_size >= 16 * slab) RUN_JS(16);
    else if (ws_size >=  8 * slab) RUN_JS(8);
    else if (ws_size >=  4 * slab) RUN_JS(4);
    else if (ws_size >=  2 * slab) RUN_JS(2);
    else                           RUN_JS(1);
#undef RUN_JS
}